// Round 2
// baseline (1728.675 us; speedup 1.0000x reference)
//
#include <hip/hip_runtime.h>
#include <hip/hip_bf16.h>
#include <math.h>

typedef __bf16 bf16;
typedef __bf16 bf16x8 __attribute__((ext_vector_type(8)));
typedef float f32x4 __attribute__((ext_vector_type(4)));

#define C_DIM 512
#define S_DIM 8192

// ---------------- Kernel 0: dtype detect ---------------------------------
// Even-indexed 16-bit halves: bf16 data -> sane exponents; fp32 data -> the
// low mantissa bits of floats -> uniform random exponents.
__global__ void detect_kernel(const unsigned short* __restrict__ xu, int* __restrict__ flag) {
    if (threadIdx.x == 0 && blockIdx.x == 0) {
        int votes = 0;
        for (int j = 0; j < 128; ++j) {
            unsigned e = (xu[2 * j] >> 7) & 0xFF;
            if (e >= 90 && e <= 140) votes++;
        }
        *flag = (votes >= 96) ? 1 : 0;   // 1 = bf16 inputs, 0 = fp32 inputs
    }
}

// ---------------- Kernel 0b: weight -> bf16 conversion -------------------
__global__ __launch_bounds__(256) void convert_kernel(const void* __restrict__ src,
                                                      bf16* __restrict__ dst, int n,
                                                      const int* __restrict__ flag) {
    int i = blockIdx.x * 256 + threadIdx.x;
    if (i >= n) return;
    if (*flag) {
        volatile const bf16* s = (volatile const bf16*)src;
        dst[i] = s[i];
    } else {
        volatile const float* s = (volatile const float*)src;
        dst[i] = (bf16)s[i];
    }
}

// ---------------- Kernel 1: per-token inverse RMS norm -------------------
__global__ __launch_bounds__(256) void rms_kernel(const void* __restrict__ x,
                                                  float* __restrict__ r,
                                                  const int* __restrict__ flag) {
    int g = blockIdx.x * 256 + threadIdx.x;   // global token
    int b = g >> 13;
    int s = g & 8191;
    float acc = 0.f;
    if (*flag) {
        const bf16* xp = (const bf16*)x + (size_t)b * C_DIM * S_DIM + s;
        for (int c = 0; c < C_DIM; ++c) { float v = (float)xp[(size_t)c * S_DIM]; acc += v * v; }
    } else {
        const float* xp = (const float*)x + (size_t)b * C_DIM * S_DIM + s;
        for (int c = 0; c < C_DIM; ++c) { float v = xp[(size_t)c * S_DIM]; acc += v * v; }
    }
    r[g] = 22.627416997969522f / fmaxf(sqrtf(acc), 1e-12f);  // sqrt(512)/max(n,eps)
}

// ------------- Kernel 2: transpose+scale -> hn[b][s][c] (token-major) ----
__global__ __launch_bounds__(256) void hn_kernel(const void* __restrict__ x,
                                                 const void* __restrict__ gamma,
                                                 const float* __restrict__ r,
                                                 bf16* __restrict__ hn,
                                                 const int* __restrict__ flag) {
    __shared__ float tile[64][65];
    int f  = *flag;
    int b  = blockIdx.z;
    int c0 = blockIdx.y * 64;
    int s0 = blockIdx.x * 64;
    int col = threadIdx.x & 63;
    int row = threadIdx.x >> 6;   // 0..3
    if (f) {
        const bf16* xp = (const bf16*)x + ((size_t)b * C_DIM + c0) * S_DIM + s0;
        for (int i = 0; i < 16; ++i)
            tile[row + i * 4][col] = (float)xp[(size_t)(row + i * 4) * S_DIM + col];
    } else {
        const float* xp = (const float*)x + ((size_t)b * C_DIM + c0) * S_DIM + s0;
        for (int i = 0; i < 16; ++i)
            tile[row + i * 4][col] = xp[(size_t)(row + i * 4) * S_DIM + col];
    }
    __syncthreads();
    float g;
    if (f) g = (float)((const bf16*)gamma)[c0 + col];
    else   g = ((const float*)gamma)[c0 + col];
    bf16* hp = hn + ((size_t)b * S_DIM + s0) * C_DIM + c0;
    for (int i = 0; i < 16; ++i) {
        int s_l = row + i * 4;
        float rv = r[b * S_DIM + s0 + s_l];
        hp[(size_t)s_l * C_DIM + col] = (bf16)(tile[col][s_l] * rv * g);
    }
}

// ------------- Kernel 3: GEMM  out[m][n] = A[m][:] . W[n][:] + bias -------
// A: [M=16384, K=512] row-major. W (bf16): [N=512, K=512] row-major.
// mode 0: out bf16 token-major [m][n]      (q, k)
// mode 1: out bf16 transposed  [b][n][s]   (v -> vt)
// mode 2: out (dtype per flag) transposed + residual from x
__global__ __launch_bounds__(256, 2) void gemm_kernel(const bf16* __restrict__ A,
                                                      const bf16* __restrict__ W,
                                                      const void* __restrict__ bias,
                                                      const void* __restrict__ resid,
                                                      void* __restrict__ out,
                                                      int mode,
                                                      const int* __restrict__ flag) {
    __shared__ bf16 As[128 * 40];
    __shared__ bf16 Bs[128 * 40];
    int f  = *flag;
    int m0 = blockIdx.x * 128;
    int n0 = blockIdx.y * 128;
    int tid  = threadIdx.x;
    int lane = tid & 63;
    int wave = tid >> 6;            // 0..3
    int wm = (wave & 1) * 64;
    int wn = (wave >> 1) * 64;
    int l15  = lane & 15;
    int quad = lane >> 4;

    f32x4 acc[4][4] = {};
    for (int k0 = 0; k0 < C_DIM; k0 += 32) {
        __syncthreads();
        for (int u = tid; u < 512; u += 256) {
            int rrow = u >> 2;
            int cc = (u & 3) * 8;
            *(bf16x8*)&As[rrow * 40 + cc] =
                *(const bf16x8*)&A[(size_t)(m0 + rrow) * C_DIM + k0 + cc];
            *(bf16x8*)&Bs[rrow * 40 + cc] =
                *(const bf16x8*)&W[(size_t)(n0 + rrow) * C_DIM + k0 + cc];
        }
        __syncthreads();
        bf16x8 af[4], bfr[4];
#pragma unroll
        for (int i = 0; i < 4; ++i)
            af[i] = *(bf16x8*)&As[(wm + i * 16 + l15) * 40 + quad * 8];
#pragma unroll
        for (int j = 0; j < 4; ++j)
            bfr[j] = *(bf16x8*)&Bs[(wn + j * 16 + l15) * 40 + quad * 8];
#pragma unroll
        for (int i = 0; i < 4; ++i)
#pragma unroll
            for (int j = 0; j < 4; ++j)
                acc[i][j] = __builtin_amdgcn_mfma_f32_16x16x32_bf16(af[i], bfr[j], acc[i][j], 0, 0, 0);
    }
    // epilogue
    if (mode == 0) {
        bf16* op = (bf16*)out;
#pragma unroll
        for (int i = 0; i < 4; ++i)
#pragma unroll
            for (int j = 0; j < 4; ++j)
#pragma unroll
                for (int rg = 0; rg < 4; ++rg) {
                    int m = m0 + wm + i * 16 + quad * 4 + rg;
                    int n = n0 + wn + j * 16 + l15;
                    float bv = f ? (float)((const bf16*)bias)[n] : ((const float*)bias)[n];
                    op[(size_t)m * C_DIM + n] = (bf16)(acc[i][j][rg] + bv);
                }
    } else if (mode == 1) {
        bf16* op = (bf16*)out;
#pragma unroll
        for (int i = 0; i < 4; ++i)
#pragma unroll
            for (int j = 0; j < 4; ++j)
#pragma unroll
                for (int rg = 0; rg < 4; ++rg) {
                    int m = m0 + wm + i * 16 + quad * 4 + rg;
                    int n = n0 + wn + j * 16 + l15;
                    float bv = f ? (float)((const bf16*)bias)[n] : ((const float*)bias)[n];
                    int b = m >> 13, s = m & 8191;
                    op[((size_t)b * C_DIM + n) * S_DIM + s] = (bf16)(acc[i][j][rg] + bv);
                }
    } else if (f) {  // mode 2, bf16 output
        bf16* op = (bf16*)out;
        const bf16* rp = (const bf16*)resid;
#pragma unroll
        for (int i = 0; i < 4; ++i)
#pragma unroll
            for (int j = 0; j < 4; ++j)
#pragma unroll
                for (int rg = 0; rg < 4; ++rg) {
                    int m = m0 + wm + i * 16 + quad * 4 + rg;
                    int n = n0 + wn + j * 16 + l15;
                    float bv = (float)((const bf16*)bias)[n];
                    int b = m >> 13, s = m & 8191;
                    size_t idx = ((size_t)b * C_DIM + n) * S_DIM + s;
                    op[idx] = (bf16)(acc[i][j][rg] + bv + (float)rp[idx]);
                }
    } else {        // mode 2, fp32 output
        float* op = (float*)out;
        const float* rp = (const float*)resid;
#pragma unroll
        for (int i = 0; i < 4; ++i)
#pragma unroll
            for (int j = 0; j < 4; ++j)
#pragma unroll
                for (int rg = 0; rg < 4; ++rg) {
                    int m = m0 + wm + i * 16 + quad * 4 + rg;
                    int n = n0 + wn + j * 16 + l15;
                    float bv = ((const float*)bias)[n];
                    int b = m >> 13, s = m & 8191;
                    size_t idx = ((size_t)b * C_DIM + n) * S_DIM + s;
                    op[idx] = acc[i][j][rg] + bv + rp[idx];
                }
    }
}

// ------------- Kernel 4: flash attention, 64 queries/block ---------------
// q,k: token-major [b][s][c].  vt: transposed [b][c][s].  o: token-major.
__global__ __launch_bounds__(256, 1) void attn_kernel(const bf16* __restrict__ q,
                                                      const bf16* __restrict__ k,
                                                      const bf16* __restrict__ vt,
                                                      bf16* __restrict__ o) {
    __shared__ bf16 Ks[32 * 520];    // 32 keys x 512 c, stride 520
    __shared__ bf16 Vs[256 * 40];    // half of V^T: 256 d rows x 32 keys, stride 40
    __shared__ bf16 Ps[4 * 16 * 40]; // per-wave P scratch, stride 40
    int b  = blockIdx.y;
    int q0 = blockIdx.x * 64;
    int tid  = threadIdx.x;
    int lane = tid & 63;
    int wave = tid >> 6;
    int l15  = lane & 15;
    int quad = lane >> 4;
    int qbase = q0 + wave * 16;

    bf16x8 qf[16];
    const bf16* qp = q + (size_t)(b * S_DIM + qbase + l15) * C_DIM;
#pragma unroll
    for (int ks = 0; ks < 16; ++ks)
        qf[ks] = *(const bf16x8*)&qp[ks * 32 + quad * 8];

    f32x4 oacc[32] = {};
    float m_i[4] = {-INFINITY, -INFINITY, -INFINITY, -INFINITY};
    float l_i[4] = {0.f, 0.f, 0.f, 0.f};
    const float scale = 0.044194173824159216f;  // 1/sqrt(512)

    int limit = ((q0 >> 10) + 1) << 10;  // (frame+1)*1024
    for (int kc = 0; kc < limit; kc += 32) {
        __syncthreads();
        const bf16* kp = k + (size_t)(b * S_DIM + kc) * C_DIM;
        for (int u = tid; u < 2048; u += 256) {
            int key = u >> 6;
            int cc = (u & 63) * 8;
            *(bf16x8*)&Ks[key * 520 + cc] = *(const bf16x8*)&kp[(size_t)key * C_DIM + cc];
        }
        const bf16* vp = vt + (size_t)b * C_DIM * S_DIM + kc;
        for (int u = tid; u < 1024; u += 256) {
            int cc = u >> 2;
            int koff = (u & 3) * 8;
            *(bf16x8*)&Vs[cc * 40 + koff] = *(const bf16x8*)&vp[(size_t)cc * S_DIM + koff];
        }
        __syncthreads();
        f32x4 st[2] = {};
#pragma unroll
        for (int nt = 0; nt < 2; ++nt) {
#pragma unroll
            for (int ks = 0; ks < 16; ++ks) {
                bf16x8 kf = *(bf16x8*)&Ks[(nt * 16 + l15) * 520 + ks * 32 + quad * 8];
                st[nt] = __builtin_amdgcn_mfma_f32_16x16x32_bf16(qf[ks], kf, st[nt], 0, 0, 0);
            }
        }
        float p0[4], p1[4], alpha[4];
#pragma unroll
        for (int rg = 0; rg < 4; ++rg) {
            float s0 = st[0][rg] * scale;
            float s1 = st[1][rg] * scale;
            float mx = fmaxf(s0, s1);
            for (int d = 1; d < 16; d <<= 1)
                mx = fmaxf(mx, __shfl_xor(mx, d, 16));
            float mn = fmaxf(m_i[rg], mx);
            alpha[rg] = expf(m_i[rg] - mn);
            m_i[rg] = mn;
            p0[rg] = expf(s0 - mn);
            p1[rg] = expf(s1 - mn);
            float rs = p0[rg] + p1[rg];
            for (int d = 1; d < 16; d <<= 1)
                rs += __shfl_xor(rs, d, 16);
            l_i[rg] = l_i[rg] * alpha[rg] + rs;
        }
        bf16* pw = &Ps[wave * 16 * 40];
#pragma unroll
        for (int rg = 0; rg < 4; ++rg) {
            pw[(quad * 4 + rg) * 40 + l15] = (bf16)p0[rg];
            pw[(quad * 4 + rg) * 40 + 16 + l15] = (bf16)p1[rg];
        }
        __syncthreads();
        bf16x8 pf = *(bf16x8*)&pw[l15 * 40 + quad * 8];
#pragma unroll
        for (int dn = 0; dn < 32; ++dn)
#pragma unroll
            for (int rg = 0; rg < 4; ++rg)
                oacc[dn][rg] *= alpha[rg];
#pragma unroll
        for (int dn = 0; dn < 16; ++dn) {
            bf16x8 vf = *(bf16x8*)&Vs[(dn * 16 + l15) * 40 + quad * 8];
            oacc[dn] = __builtin_amdgcn_mfma_f32_16x16x32_bf16(pf, vf, oacc[dn], 0, 0, 0);
        }
        __syncthreads();
        for (int u = tid; u < 1024; u += 256) {
            int cc = u >> 2;
            int koff = (u & 3) * 8;
            *(bf16x8*)&Vs[cc * 40 + koff] =
                *(const bf16x8*)&vp[(size_t)(cc + 256) * S_DIM + koff];
        }
        __syncthreads();
#pragma unroll
        for (int dn = 16; dn < 32; ++dn) {
            bf16x8 vf = *(bf16x8*)&Vs[((dn - 16) * 16 + l15) * 40 + quad * 8];
            oacc[dn] = __builtin_amdgcn_mfma_f32_16x16x32_bf16(pf, vf, oacc[dn], 0, 0, 0);
        }
    }
    bf16* op = o + (size_t)(b * S_DIM + qbase) * C_DIM;
#pragma unroll
    for (int dn = 0; dn < 32; ++dn) {
#pragma unroll
        for (int rg = 0; rg < 4; ++rg) {
            int m = quad * 4 + rg;
            int d = dn * 16 + l15;
            op[(size_t)m * C_DIM + d] = (bf16)(oacc[dn][rg] / l_i[rg]);
        }
    }
}

extern "C" void kernel_launch(void* const* d_in, const int* in_sizes, int n_in,
                              void* d_out, int out_size, void* d_ws, size_t ws_size,
                              hipStream_t stream) {
    const void* x     = d_in[0];
    const void* gamma = d_in[1];
    const void* wq    = d_in[2];
    const void* bq    = d_in[3];
    const void* wk    = d_in[4];
    const void* bk    = d_in[5];
    const void* wv    = d_in[6];
    const void* bv    = d_in[7];
    const void* wo    = d_in[8];
    const void* bo    = d_in[9];

    char* ws = (char*)d_ws;
    int*   flag  = (int*)ws;
    float* r_buf = (float*)(ws + 4096);                 // 64 KB
    bf16* wqb = (bf16*)(ws + 0x20000);                  // 512 KB each
    bf16* wkb = (bf16*)(ws + 0xA0000);
    bf16* wvb = (bf16*)(ws + 0x120000);
    bf16* wob = (bf16*)(ws + 0x1A0000);
    bf16* hn  = (bf16*)(ws + 0x400000);                 // 16 MB each
    bf16* qb  = (bf16*)(ws + 0x400000 + 0x1000000ull * 1);
    bf16* kb  = (bf16*)(ws + 0x400000 + 0x1000000ull * 2);
    bf16* vtb = (bf16*)(ws + 0x400000 + 0x1000000ull * 3);
    bf16* ob  = (bf16*)(ws + 0x400000 + 0x1000000ull * 4);

    hipLaunchKernelGGL(detect_kernel, dim3(1), dim3(64), 0, stream,
                       (const unsigned short*)x, flag);
    hipLaunchKernelGGL(convert_kernel, dim3(1024), dim3(256), 0, stream, wq, wqb, 262144, flag);
    hipLaunchKernelGGL(convert_kernel, dim3(1024), dim3(256), 0, stream, wk, wkb, 262144, flag);
    hipLaunchKernelGGL(convert_kernel, dim3(1024), dim3(256), 0, stream, wv, wvb, 262144, flag);
    hipLaunchKernelGGL(convert_kernel, dim3(1024), dim3(256), 0, stream, wo, wob, 262144, flag);
    hipLaunchKernelGGL(rms_kernel, dim3(64), dim3(256), 0, stream, x, r_buf, flag);
    hipLaunchKernelGGL(hn_kernel, dim3(128, 8, 2), dim3(256), 0, stream, x, gamma, r_buf, hn, flag);
    hipLaunchKernelGGL(gemm_kernel, dim3(128, 4), dim3(256), 0, stream, hn, wqb, bq, (const void*)nullptr, qb, 0, flag);
    hipLaunchKernelGGL(gemm_kernel, dim3(128, 4), dim3(256), 0, stream, hn, wkb, bk, (const void*)nullptr, kb, 0, flag);
    hipLaunchKernelGGL(gemm_kernel, dim3(128, 4), dim3(256), 0, stream, hn, wvb, bv, (const void*)nullptr, vtb, 1, flag);
    hipLaunchKernelGGL(attn_kernel, dim3(128, 2), dim3(256), 0, stream, qb, kb, vtb, ob);
    hipLaunchKernelGGL(gemm_kernel, dim3(128, 4), dim3(256), 0, stream, ob, wob, bo, x, d_out, 2, flag);
}

// Round 3
// 996.475 us; speedup vs baseline: 1.7348x; 1.7348x over previous
//
#include <hip/hip_runtime.h>
#include <hip/hip_bf16.h>
#include <math.h>

typedef __bf16 bf16;
typedef __bf16 bf16x8 __attribute__((ext_vector_type(8)));
typedef float f32x4 __attribute__((ext_vector_type(4)));

#define C_DIM 512
#define S_DIM 8192

// ---------------- Kernel 0: dtype detect ---------------------------------
__global__ void detect_kernel(const unsigned short* __restrict__ xu, int* __restrict__ flag) {
    if (threadIdx.x == 0 && blockIdx.x == 0) {
        int votes = 0;
        for (int j = 0; j < 128; ++j) {
            unsigned e = (xu[2 * j] >> 7) & 0xFF;
            if (e >= 90 && e <= 140) votes++;
        }
        *flag = (votes >= 96) ? 1 : 0;   // 1 = bf16 inputs, 0 = fp32 inputs
    }
}

// ---------------- Kernel 0b: weight -> bf16 conversion -------------------
__global__ __launch_bounds__(256) void convert_kernel(const void* __restrict__ src,
                                                      bf16* __restrict__ dst, int n,
                                                      const int* __restrict__ flag) {
    int i = blockIdx.x * 256 + threadIdx.x;
    if (i >= n) return;
    if (*flag) {
        volatile const bf16* s = (volatile const bf16*)src;
        dst[i] = s[i];
    } else {
        volatile const float* s = (volatile const float*)src;
        dst[i] = (bf16)s[i];
    }
}

// ---------------- Kernel 1: per-token inverse RMS norm -------------------
__global__ __launch_bounds__(256) void rms_kernel(const void* __restrict__ x,
                                                  float* __restrict__ r,
                                                  const int* __restrict__ flag) {
    int g = blockIdx.x * 256 + threadIdx.x;
    int b = g >> 13;
    int s = g & 8191;
    float acc = 0.f;
    if (*flag) {
        const bf16* xp = (const bf16*)x + (size_t)b * C_DIM * S_DIM + s;
        for (int c = 0; c < C_DIM; ++c) { float v = (float)xp[(size_t)c * S_DIM]; acc += v * v; }
    } else {
        const float* xp = (const float*)x + (size_t)b * C_DIM * S_DIM + s;
        for (int c = 0; c < C_DIM; ++c) { float v = xp[(size_t)c * S_DIM]; acc += v * v; }
    }
    r[g] = 22.627416997969522f / fmaxf(sqrtf(acc), 1e-12f);
}

// ------------- Kernel 2: transpose+scale -> hn[b][s][c] (token-major) ----
__global__ __launch_bounds__(256) void hn_kernel(const void* __restrict__ x,
                                                 const void* __restrict__ gamma,
                                                 const float* __restrict__ r,
                                                 bf16* __restrict__ hn,
                                                 const int* __restrict__ flag) {
    __shared__ float tile[64][65];
    int f  = *flag;
    int b  = blockIdx.z;
    int c0 = blockIdx.y * 64;
    int s0 = blockIdx.x * 64;
    int col = threadIdx.x & 63;
    int row = threadIdx.x >> 6;
    if (f) {
        const bf16* xp = (const bf16*)x + ((size_t)b * C_DIM + c0) * S_DIM + s0;
        for (int i = 0; i < 16; ++i)
            tile[row + i * 4][col] = (float)xp[(size_t)(row + i * 4) * S_DIM + col];
    } else {
        const float* xp = (const float*)x + ((size_t)b * C_DIM + c0) * S_DIM + s0;
        for (int i = 0; i < 16; ++i)
            tile[row + i * 4][col] = xp[(size_t)(row + i * 4) * S_DIM + col];
    }
    __syncthreads();
    float g;
    if (f) g = (float)((const bf16*)gamma)[c0 + col];
    else   g = ((const float*)gamma)[c0 + col];
    bf16* hp = hn + ((size_t)b * S_DIM + s0) * C_DIM + c0;
    for (int i = 0; i < 16; ++i) {
        int s_l = row + i * 4;
        float rv = r[b * S_DIM + s0 + s_l];
        hp[(size_t)s_l * C_DIM + col] = (bf16)(tile[col][s_l] * rv * g);
    }
}

// ------------- Kernel 3: GEMM  out[m][n] = A[m][:] . W[n][:] + bias -------
__global__ __launch_bounds__(256, 2) void gemm_kernel(const bf16* __restrict__ A,
                                                      const bf16* __restrict__ W,
                                                      const void* __restrict__ bias,
                                                      const void* __restrict__ resid,
                                                      void* __restrict__ out,
                                                      int mode,
                                                      const int* __restrict__ flag) {
    __shared__ bf16 As[128 * 40];
    __shared__ bf16 Bs[128 * 40];
    int f  = *flag;
    int m0 = blockIdx.x * 128;
    int n0 = blockIdx.y * 128;
    int tid  = threadIdx.x;
    int lane = tid & 63;
    int wave = tid >> 6;
    int wm = (wave & 1) * 64;
    int wn = (wave >> 1) * 64;
    int l15  = lane & 15;
    int quad = lane >> 4;

    f32x4 acc[4][4] = {};
    for (int k0 = 0; k0 < C_DIM; k0 += 32) {
        __syncthreads();
        for (int u = tid; u < 512; u += 256) {
            int rrow = u >> 2;
            int cc = (u & 3) * 8;
            *(bf16x8*)&As[rrow * 40 + cc] =
                *(const bf16x8*)&A[(size_t)(m0 + rrow) * C_DIM + k0 + cc];
            *(bf16x8*)&Bs[rrow * 40 + cc] =
                *(const bf16x8*)&W[(size_t)(n0 + rrow) * C_DIM + k0 + cc];
        }
        __syncthreads();
        bf16x8 af[4], bfr[4];
#pragma unroll
        for (int i = 0; i < 4; ++i)
            af[i] = *(bf16x8*)&As[(wm + i * 16 + l15) * 40 + quad * 8];
#pragma unroll
        for (int j = 0; j < 4; ++j)
            bfr[j] = *(bf16x8*)&Bs[(wn + j * 16 + l15) * 40 + quad * 8];
#pragma unroll
        for (int i = 0; i < 4; ++i)
#pragma unroll
            for (int j = 0; j < 4; ++j)
                acc[i][j] = __builtin_amdgcn_mfma_f32_16x16x32_bf16(af[i], bfr[j], acc[i][j], 0, 0, 0);
    }
    if (mode == 0) {
        bf16* op = (bf16*)out;
#pragma unroll
        for (int i = 0; i < 4; ++i)
#pragma unroll
            for (int j = 0; j < 4; ++j)
#pragma unroll
                for (int rg = 0; rg < 4; ++rg) {
                    int m = m0 + wm + i * 16 + quad * 4 + rg;
                    int n = n0 + wn + j * 16 + l15;
                    float bv = f ? (float)((const bf16*)bias)[n] : ((const float*)bias)[n];
                    op[(size_t)m * C_DIM + n] = (bf16)(acc[i][j][rg] + bv);
                }
    } else if (mode == 1) {
        bf16* op = (bf16*)out;
#pragma unroll
        for (int i = 0; i < 4; ++i)
#pragma unroll
            for (int j = 0; j < 4; ++j)
#pragma unroll
                for (int rg = 0; rg < 4; ++rg) {
                    int m = m0 + wm + i * 16 + quad * 4 + rg;
                    int n = n0 + wn + j * 16 + l15;
                    float bv = f ? (float)((const bf16*)bias)[n] : ((const float*)bias)[n];
                    int b = m >> 13, s = m & 8191;
                    op[((size_t)b * C_DIM + n) * S_DIM + s] = (bf16)(acc[i][j][rg] + bv);
                }
    } else if (f) {
        bf16* op = (bf16*)out;
        const bf16* rp = (const bf16*)resid;
#pragma unroll
        for (int i = 0; i < 4; ++i)
#pragma unroll
            for (int j = 0; j < 4; ++j)
#pragma unroll
                for (int rg = 0; rg < 4; ++rg) {
                    int m = m0 + wm + i * 16 + quad * 4 + rg;
                    int n = n0 + wn + j * 16 + l15;
                    float bv = (float)((const bf16*)bias)[n];
                    int b = m >> 13, s = m & 8191;
                    size_t idx = ((size_t)b * C_DIM + n) * S_DIM + s;
                    op[idx] = (bf16)(acc[i][j][rg] + bv + (float)rp[idx]);
                }
    } else {
        float* op = (float*)out;
        const float* rp = (const float*)resid;
#pragma unroll
        for (int i = 0; i < 4; ++i)
#pragma unroll
            for (int j = 0; j < 4; ++j)
#pragma unroll
                for (int rg = 0; rg < 4; ++rg) {
                    int m = m0 + wm + i * 16 + quad * 4 + rg;
                    int n = n0 + wn + j * 16 + l15;
                    float bv = ((const float*)bias)[n];
                    int b = m >> 13, s = m & 8191;
                    size_t idx = ((size_t)b * C_DIM + n) * S_DIM + s;
                    op[idx] = acc[i][j][rg] + bv + rp[idx];
                }
    }
}

// ------------- Kernel 4: split-K flash attention -------------------------
// Uniform unit: 64 queries x 1024 keys. split=1: 1152 blocks write normalized
// partial O (bf16) + logsumexp; split=0: 256 blocks, whole key range, write
// ob directly (fallback when ws is small).
// q,k: token-major [b][s][c].  vt: transposed [b][c][s].
#define KS_STRIDE 544   // 1088 B rows: l15 row-starts alternate bank 0/16 -> 2-way (free)
#define VS_STRIDE 36    // 72 B rows: 16 distinct row-start banks -> ~2-way
__global__ __launch_bounds__(256, 1) void attn_kernel(const bf16* __restrict__ q,
                                                      const bf16* __restrict__ k,
                                                      const bf16* __restrict__ vt,
                                                      bf16* __restrict__ part,
                                                      float* __restrict__ lse,
                                                      bf16* __restrict__ ob,
                                                      int split) {
    __shared__ bf16 Ks[32 * KS_STRIDE];    // 34,816 B
    __shared__ bf16 Vs[512 * VS_STRIDE];   // 36,864 B (full 512 channels x 32 keys)
    __shared__ bf16 Ps[4 * 16 * VS_STRIDE];// 4,608 B  -> total 76,288 B (2 blocks/CU)
    int id = blockIdx.x;
    int b, q0, kc0, kc1;
    if (split) {
        b = id / 576;
        int r = id - b * 576;
        int f = 0;
        while (8 * (f + 1) * (f + 2) <= r) ++f;      // frame 0..7
        int rr = r - 8 * f * (f + 1);
        int tif = rr / (f + 1);
        int unit = rr - tif * (f + 1);
        q0 = (f * 16 + tif) * 64;
        kc0 = unit << 10;
        kc1 = kc0 + 1024;
    } else {
        b = id >> 7;
        int t = id & 127;
        q0 = t * 64;
        kc0 = 0;
        kc1 = ((t >> 4) + 1) << 10;
    }
    int tid  = threadIdx.x;
    int lane = tid & 63;
    int wave = tid >> 6;
    int l15  = lane & 15;
    int quad = lane >> 4;
    int qbase = q0 + wave * 16;

    // Q fragments (16 K-steps covering C=512), held in registers
    bf16x8 qf[16];
    const bf16* qp = q + (size_t)(b * S_DIM + qbase + l15) * C_DIM;
#pragma unroll
    for (int ks = 0; ks < 16; ++ks)
        qf[ks] = *(const bf16x8*)&qp[ks * 32 + quad * 8];

    f32x4 oacc[32] = {};
    float m_i[4] = {-INFINITY, -INFINITY, -INFINITY, -INFINITY};
    float l_i[4] = {0.f, 0.f, 0.f, 0.f};
    const float scale = 0.044194173824159216f;  // 1/sqrt(512)

    for (int kc = kc0; kc < kc1; kc += 32) {
        __syncthreads();   // protect prev iteration's LDS reads
        // stage K: 32 keys x 512 c (one full key row per wave-iteration)
        const bf16* kp = k + (size_t)(b * S_DIM + kc) * C_DIM;
#pragma unroll
        for (int i = 0; i < 8; ++i) {
            int u = tid + i * 256;
            int key = u >> 6;
            int cc = (u & 63) * 8;
            *(bf16x8*)&Ks[key * KS_STRIDE + cc] = *(const bf16x8*)&kp[(size_t)key * C_DIM + cc];
        }
        // stage V^T: 512 channel rows x 32 keys
        const bf16* vp = vt + (size_t)b * C_DIM * S_DIM + kc;
#pragma unroll
        for (int i = 0; i < 8; ++i) {
            int u = tid + i * 256;
            int cc = u >> 2;
            int koff = (u & 3) * 8;
            *(bf16x8*)&Vs[cc * VS_STRIDE + koff] = *(const bf16x8*)&vp[(size_t)cc * S_DIM + koff];
        }
        __syncthreads();
        // S = q . k^T  (two 16-key sub-tiles)
        f32x4 st[2] = {};
#pragma unroll
        for (int nt = 0; nt < 2; ++nt) {
#pragma unroll
            for (int ks = 0; ks < 16; ++ks) {
                bf16x8 kf = *(bf16x8*)&Ks[(nt * 16 + l15) * KS_STRIDE + ks * 32 + quad * 8];
                st[nt] = __builtin_amdgcn_mfma_f32_16x16x32_bf16(qf[ks], kf, st[nt], 0, 0, 0);
            }
        }
        // online softmax (C layout: row = quad*4+rg, col = key = l15)
        float p0[4], p1[4], alpha[4];
#pragma unroll
        for (int rg = 0; rg < 4; ++rg) {
            float s0 = st[0][rg] * scale;
            float s1 = st[1][rg] * scale;
            float mx = fmaxf(s0, s1);
            for (int d = 1; d < 16; d <<= 1)
                mx = fmaxf(mx, __shfl_xor(mx, d, 16));
            float mn = fmaxf(m_i[rg], mx);
            alpha[rg] = expf(m_i[rg] - mn);
            m_i[rg] = mn;
            p0[rg] = expf(s0 - mn);
            p1[rg] = expf(s1 - mn);
            float rs = p0[rg] + p1[rg];
            for (int d = 1; d < 16; d <<= 1)
                rs += __shfl_xor(rs, d, 16);
            l_i[rg] = l_i[rg] * alpha[rg] + rs;
        }
        // P (C layout) -> per-wave LDS scratch -> A layout (same-wave, no barrier)
        bf16* pw = &Ps[wave * 16 * VS_STRIDE];
#pragma unroll
        for (int rg = 0; rg < 4; ++rg) {
            pw[(quad * 4 + rg) * VS_STRIDE + l15] = (bf16)p0[rg];
            pw[(quad * 4 + rg) * VS_STRIDE + 16 + l15] = (bf16)p1[rg];
        }
        bf16x8 pf = *(bf16x8*)&pw[l15 * VS_STRIDE + quad * 8];
        // rescale O accumulator
#pragma unroll
        for (int dn = 0; dn < 32; ++dn)
#pragma unroll
            for (int rg = 0; rg < 4; ++rg)
                oacc[dn][rg] *= alpha[rg];
        // PV over all 512 channels
#pragma unroll
        for (int dn = 0; dn < 32; ++dn) {
            bf16x8 vf = *(bf16x8*)&Vs[(dn * 16 + l15) * VS_STRIDE + quad * 8];
            oacc[dn] = __builtin_amdgcn_mfma_f32_16x16x32_bf16(pf, vf, oacc[dn], 0, 0, 0);
        }
    }
    float rinv[4];
#pragma unroll
    for (int rg = 0; rg < 4; ++rg) rinv[rg] = 1.f / l_i[rg];
    if (split) {
        bf16* pp = part + ((size_t)id * 64 + wave * 16) * C_DIM;
#pragma unroll
        for (int dn = 0; dn < 32; ++dn)
#pragma unroll
            for (int rg = 0; rg < 4; ++rg)
                pp[(size_t)(quad * 4 + rg) * C_DIM + dn * 16 + l15] =
                    (bf16)(oacc[dn][rg] * rinv[rg]);
        if (l15 == 0) {
#pragma unroll
            for (int rg = 0; rg < 4; ++rg)
                lse[id * 64 + wave * 16 + quad * 4 + rg] = m_i[rg] + logf(l_i[rg]);
        }
    } else {
        bf16* op = ob + (size_t)(b * S_DIM + qbase) * C_DIM;
#pragma unroll
        for (int dn = 0; dn < 32; ++dn)
#pragma unroll
            for (int rg = 0; rg < 4; ++rg)
                op[(size_t)(quad * 4 + rg) * C_DIM + dn * 16 + l15] =
                    (bf16)(oacc[dn][rg] * rinv[rg]);
    }
}

// ------------- Kernel 5: split-K combine ---------------------------------
__global__ __launch_bounds__(256) void combine_kernel(const bf16* __restrict__ part,
                                                      const float* __restrict__ lse,
                                                      bf16* __restrict__ ob) {
    int id = blockIdx.x;            // 0..255 (b, 64q-tile)
    int b = id >> 7, t = id & 127;
    int f = t >> 4;
    int U = f + 1;
    int pbase = b * 576 + 8 * f * (f + 1) + (t & 15) * (f + 1);
    int qq = threadIdx.x >> 2;      // 0..63
    int cr = threadIdx.x & 3;       // 128-ch segment
    float w[8];
    float M = -INFINITY;
    for (int u = 0; u < U; ++u) {
        w[u] = lse[(pbase + u) * 64 + qq];
        M = fmaxf(M, w[u]);
    }
    float D = 0.f;
    for (int u = 0; u < U; ++u) { w[u] = expf(w[u] - M); D += w[u]; }
    float Dinv = 1.f / D;
    for (int u = 0; u < U; ++u) w[u] *= Dinv;
    bf16* op = ob + (size_t)(b * S_DIM + t * 64 + qq) * C_DIM + cr * 128;
    for (int ch = 0; ch < 16; ++ch) {
        float acc[8] = {};
        for (int u = 0; u < U; ++u) {
            bf16x8 pv = *(const bf16x8*)&part[((size_t)(pbase + u) * 64 + qq) * C_DIM + cr * 128 + ch * 8];
#pragma unroll
            for (int j = 0; j < 8; ++j) acc[j] += w[u] * (float)pv[j];
        }
        bf16x8 o8;
#pragma unroll
        for (int j = 0; j < 8; ++j) o8[j] = (bf16)acc[j];
        *(bf16x8*)&op[ch * 8] = o8;
    }
}

extern "C" void kernel_launch(void* const* d_in, const int* in_sizes, int n_in,
                              void* d_out, int out_size, void* d_ws, size_t ws_size,
                              hipStream_t stream) {
    const void* x     = d_in[0];
    const void* gamma = d_in[1];
    const void* wq    = d_in[2];
    const void* bq    = d_in[3];
    const void* wk    = d_in[4];
    const void* bk    = d_in[5];
    const void* wv    = d_in[6];
    const void* bv    = d_in[7];
    const void* wo    = d_in[8];
    const void* bo    = d_in[9];

    char* ws = (char*)d_ws;
    int*   flag    = (int*)ws;
    float* r_buf   = (float*)(ws + 4096);
    bf16* wqb = (bf16*)(ws + 0x20000);
    bf16* wkb = (bf16*)(ws + 0xA0000);
    bf16* wvb = (bf16*)(ws + 0x120000);
    bf16* wob = (bf16*)(ws + 0x1A0000);
    float* lse_buf = (float*)(ws + 0x240000);            // 1152*64*4 = 288 KB
    bf16* hn  = (bf16*)(ws + 0x400000);
    bf16* qb  = (bf16*)(ws + 0x400000 + 0x1000000ull * 1);
    bf16* kb  = (bf16*)(ws + 0x400000 + 0x1000000ull * 2);
    bf16* vtb = (bf16*)(ws + 0x400000 + 0x1000000ull * 3);
    bf16* ob  = (bf16*)(ws + 0x400000 + 0x1000000ull * 4);
    bf16* part = (bf16*)(ws + 0x5400000);                // 1152*64*512*2 = 75.5 MB

    const size_t ws_needed_split = 0x5400000ull + 1152ull * 64 * 512 * 2;
    int split = (ws_size >= ws_needed_split) ? 1 : 0;    // deterministic per session

    hipLaunchKernelGGL(detect_kernel, dim3(1), dim3(64), 0, stream,
                       (const unsigned short*)x, flag);
    hipLaunchKernelGGL(convert_kernel, dim3(1024), dim3(256), 0, stream, wq, wqb, 262144, flag);
    hipLaunchKernelGGL(convert_kernel, dim3(1024), dim3(256), 0, stream, wk, wkb, 262144, flag);
    hipLaunchKernelGGL(convert_kernel, dim3(1024), dim3(256), 0, stream, wv, wvb, 262144, flag);
    hipLaunchKernelGGL(convert_kernel, dim3(1024), dim3(256), 0, stream, wo, wob, 262144, flag);
    hipLaunchKernelGGL(rms_kernel, dim3(64), dim3(256), 0, stream, x, r_buf, flag);
    hipLaunchKernelGGL(hn_kernel, dim3(128, 8, 2), dim3(256), 0, stream, x, gamma, r_buf, hn, flag);
    hipLaunchKernelGGL(gemm_kernel, dim3(128, 4), dim3(256), 0, stream, hn, wqb, bq, (const void*)nullptr, qb, 0, flag);
    hipLaunchKernelGGL(gemm_kernel, dim3(128, 4), dim3(256), 0, stream, hn, wkb, bk, (const void*)nullptr, kb, 0, flag);
    hipLaunchKernelGGL(gemm_kernel, dim3(128, 4), dim3(256), 0, stream, hn, wvb, bv, (const void*)nullptr, vtb, 1, flag);
    hipLaunchKernelGGL(attn_kernel, dim3(split ? 1152 : 256), dim3(256), 0, stream,
                       qb, kb, vtb, part, lse_buf, ob, split);
    if (split)
        hipLaunchKernelGGL(combine_kernel, dim3(256), dim3(256), 0, stream, part, lse_buf, ob);
    hipLaunchKernelGGL(gemm_kernel, dim3(128, 4), dim3(256), 0, stream, ob, wob, bo, x, d_out, 2, flag);
}